// Round 7
// baseline (237.608 us; speedup 1.0000x reference)
//
#include <hip/hip_runtime.h>

typedef __bf16 v8bf __attribute__((ext_vector_type(8)));
typedef float v4f __attribute__((ext_vector_type(4)));
typedef unsigned short u16x8 __attribute__((ext_vector_type(8)));

__device__ __forceinline__ unsigned short f2bf(float f) {
    unsigned int u = __float_as_uint(f);
    u += 0x7FFFu + ((u >> 16) & 1u);   // round-to-nearest-even
    return (unsigned short)(u >> 16);
}

__device__ __forceinline__ v8bf ld_bf8(const unsigned short* p) {
    u16x8 r = *(const u16x8*)p;
    return __builtin_bit_cast(v8bf, r);
}

__device__ __forceinline__ void gload16(const void* g, void* l) {
    __builtin_amdgcn_global_load_lds(
        (const __attribute__((address_space(1))) void*)g,
        (__attribute__((address_space(3))) void*)l, 16, 0, 0);
}

// ---------------- Kernel A: build V = U[:, :64] ----------------
// 4 blocks x 1024 thr. Block = (row-half rb, col-half cb): owns rows 512rb..+512,
// cols 32cb..+32. Wave w computes 2 full columns in registers (product-state
// formula + RY1 butterflies — verified math from r5/r6), keeps its row-half in
// LDS; block then writes 64-B-aligned full sectors, block-exclusive (no RFO,
// no cross-block/cross-XCD line sharing — the r2..r6 store-pattern suspect).
__global__ __launch_bounds__(1024, 1) void build_V(
        const float* __restrict__ rx0, const float* __restrict__ ry0,
        const float* __restrict__ ry1,
        unsigned short* __restrict__ Vre, unsigned short* __restrict__ Vim)
{
    __shared__ unsigned int colbuf[512][33];
    const int t = threadIdx.x;
    const int w = t >> 6, lane = t & 63;
    const int rb = blockIdx.x & 1;
    const int cb = blockIdx.x >> 1;

    // hoist param loads (not trig) once
    float phx[10], phy[10], c1[10], s1[10];
    #pragma unroll
    for (int j = 0; j < 10; ++j) {
        phx[j] = 0.5f * rx0[j];
        phy[j] = 0.5f * ry0[j];
        float h = 0.5f * ry1[j];
        c1[j] = cosf(h); s1[j] = sinf(h);
    }

    // kk[q] = Pinv(lane + 64q): CNOT-ring inverse (column-independent)
    int kk[16];
    #pragma unroll
    for (int q = 0; q < 16; ++q) {
        int k = lane + (q << 6);
        #pragma unroll
        for (int jj = 9; jj >= 0; --jj) {
            int cbit = 9 - jj, tbit = 9 - ((jj + 1) % 10);
            k ^= ((k >> cbit) & 1) << tbit;
        }
        kk[q] = k;
    }

    for (int ci = 0; ci < 2; ++ci) {
        const int c = cb * 32 + w * 2 + ci;

        float ar[16], ai[16];
        #pragma unroll
        for (int q = 0; q < 16; ++q) { ar[q] = 1.f; ai[q] = 0.f; }

        #pragma unroll
        for (int j = 0; j < 10; ++j) {
            float cx = cosf(phx[j]), sx = sinf(phx[j]);
            float cy = cosf(phy[j]), sy = sinf(phy[j]);
            int cbit = (c >> (9 - j)) & 1;
            float g0r = cbit ? (-sy * cx) : (cy * cx);
            float g0i = cbit ? (-cy * sx) : (sy * sx);
            float g1r = cbit ? (cy * cx)  : (sy * cx);
            float g1i = cbit ? (-sy * sx) : (-cy * sx);
            int p = 9 - j;
            #pragma unroll
            for (int q = 0; q < 16; ++q) {
                int kb = (kk[q] >> p) & 1;
                float fr = kb ? g1r : g0r;
                float fi = kb ? g1i : g0i;
                float nr = ar[q] * fr - ai[q] * fi;
                float ni = ar[q] * fi + ai[q] * fr;
                ar[q] = nr; ai[q] = ni;
            }
        }
        // RY1 on m bits 6..9 (q bits, qubit j = 3-b)
        #pragma unroll
        for (int b = 0; b < 4; ++b) {
            float cy = c1[3 - b], sy = s1[3 - b];
            #pragma unroll
            for (int q = 0; q < 16; ++q) {
                if (q & (1 << b)) continue;
                int q2 = q | (1 << b);
                float A_r = ar[q], A_i = ai[q], B_r = ar[q2], B_i = ai[q2];
                ar[q]  = cy * A_r - sy * B_r;  ai[q]  = cy * A_i - sy * B_i;
                ar[q2] = sy * A_r + cy * B_r;  ai[q2] = sy * A_i + cy * B_i;
            }
        }
        // RY1 on m bits 0..5 (lane bits, qubit j = 9-p) via shfl_xor
        #pragma unroll
        for (int p = 5; p >= 0; --p) {
            float cy = c1[9 - p], sy = s1[9 - p];
            int hi = (lane >> p) & 1;
            #pragma unroll
            for (int q = 0; q < 16; ++q) {
                float orr = __shfl_xor(ar[q], 1 << p);
                float oii = __shfl_xor(ai[q], 1 << p);
                ar[q] = hi ? (sy * orr + cy * ar[q]) : (cy * ar[q] - sy * orr);
                ai[q] = hi ? (sy * oii + cy * ai[q]) : (cy * ai[q] - sy * oii);
            }
        }
        // keep this block's row-half (static indices in each uniform branch)
        const int cl = w * 2 + ci;
        if (rb == 0) {
            #pragma unroll
            for (int qq = 0; qq < 8; ++qq)
                colbuf[lane + (qq << 6)][cl] =
                    (unsigned)f2bf(ar[qq]) | ((unsigned)f2bf(ai[qq]) << 16);
        } else {
            #pragma unroll
            for (int qq = 0; qq < 8; ++qq)
                colbuf[lane + (qq << 6)][cl] =
                    (unsigned)f2bf(ar[8 + qq]) | ((unsigned)f2bf(ai[8 + qq]) << 16);
        }
    }
    __syncthreads();

    // block-exclusive, 64B-sector writes: thread t -> (row r, 16-col half h2)
    {
        const int r = t >> 1, h2 = t & 1;
        unsigned int tmp[16];
        #pragma unroll
        for (int k = 0; k < 16; ++k) tmp[k] = colbuf[r][h2 * 16 + k];
        u16x8 rlo, rhi, ilo, ihi;
        #pragma unroll
        for (int k = 0; k < 8; ++k) {
            rlo[k] = (unsigned short)tmp[k];
            rhi[k] = (unsigned short)tmp[8 + k];
            ilo[k] = (unsigned short)(tmp[k] >> 16);
            ihi[k] = (unsigned short)(tmp[8 + k] >> 16);
        }
        size_t base = (size_t)(512 * rb + r) * 64 + 32 * cb + 16 * h2;
        *(u16x8*)(Vre + base)     = rlo;
        *(u16x8*)(Vre + base + 8) = rhi;
        *(u16x8*)(Vim + base)     = ilo;
        *(u16x8*)(Vim + base + 8) = ihi;
    }
}

// ---------------- Kernel B: out = WHT_7( fold_128( |xn @ VS^T|^2 ) ) ----------------
// VS = [Vre; Vim] stacked 2048x64 = 32 chunks of 64x64. Block = 4 waves, each
// wave owns a 16-token tile and processes ALL 32 chunks (V shared via LDS ->
// L2 volume 4x lower). T3+T4: global_load_lds staging, depth 4, counted
// vmcnt(4) (never 0 mid-loop), raw s_barrier. XOR-swizzle on both sides
// (rule #21) kills the stride-128B ds_read bank conflict.
#define MFMA16(a, b, c) __builtin_amdgcn_mfma_f32_16x16x32_bf16(a, b, c, 0, 0, 0)

__global__ __launch_bounds__(256, 4) void qsa_fused(
        const float* __restrict__ x,
        const unsigned short* __restrict__ VS,
        float* __restrict__ out)
{
    __shared__ alignas(64) unsigned short vs[4][4096];   // 4 slots x 8 KB

    const int tid = threadIdx.x;
    const int w = tid >> 6;
    const int l = tid & 63;
    const int l15 = l & 15, lh = l >> 4;
    const int tb = blockIdx.x * 64 + w * 16;   // this wave's 16 token rows

    // ---- load + normalize 16 tokens into A-fragments ----
    const float* xrow = x + (size_t)(tb + l15) * 64;
    float4 v0 = *(const float4*)(xrow + lh * 8);
    float4 v1 = *(const float4*)(xrow + lh * 8 + 4);
    float4 v2 = *(const float4*)(xrow + 32 + lh * 8);
    float4 v3 = *(const float4*)(xrow + 32 + lh * 8 + 4);
    float ss = v0.x*v0.x + v0.y*v0.y + v0.z*v0.z + v0.w*v0.w
             + v1.x*v1.x + v1.y*v1.y + v1.z*v1.z + v1.w*v1.w
             + v2.x*v2.x + v2.y*v2.y + v2.z*v2.z + v2.w*v2.w
             + v3.x*v3.x + v3.y*v3.y + v3.z*v3.z + v3.w*v3.w;
    ss += __shfl_xor(ss, 16);
    ss += __shfl_xor(ss, 32);
    float rn = rsqrtf(ss);
    u16x8 ua0, ua1;
    ua0[0]=f2bf(v0.x*rn); ua0[1]=f2bf(v0.y*rn); ua0[2]=f2bf(v0.z*rn); ua0[3]=f2bf(v0.w*rn);
    ua0[4]=f2bf(v1.x*rn); ua0[5]=f2bf(v1.y*rn); ua0[6]=f2bf(v1.z*rn); ua0[7]=f2bf(v1.w*rn);
    ua1[0]=f2bf(v2.x*rn); ua1[1]=f2bf(v2.y*rn); ua1[2]=f2bf(v2.z*rn); ua1[3]=f2bf(v2.w*rn);
    ua1[4]=f2bf(v3.x*rn); ua1[5]=f2bf(v3.y*rn); ua1[6]=f2bf(v3.z*rn); ua1[7]=f2bf(v3.w*rn);
    const v8bf a0 = __builtin_bit_cast(v8bf, ua0);
    const v8bf a1 = __builtin_bit_cast(v8bf, ua1);
    __builtin_amdgcn_sched_barrier(0);   // keep x-loads fully drained before staging

    const char* vsg = (const char*)VS;

    // stage: wave w issues insts i = 2w, 2w+1 (1 KB each) for chunk cc.
    // LDS dest linear; SOURCE pre-swizzled with the same involution the
    // ds_read applies: o ^= ((row&7)<<4), row = o>>7  (rule #21).
#define STAGE2(cc) do {                                                       \
        unsigned _o0 = ((unsigned)(2*w) << 10) + ((unsigned)l << 4);          \
        unsigned _o1 = _o0 + 1024u;                                           \
        gload16(vsg + ((size_t)(cc) << 13) + (_o0 ^ (((_o0 >> 7) & 7u) << 4)),\
                &vs[(cc) & 3][(2*w) << 9]);                                   \
        gload16(vsg + ((size_t)(cc) << 13) + (_o1 ^ (((_o1 >> 7) & 7u) << 4)),\
                &vs[(cc) & 3][((2*w) << 9) + 512]);                           \
    } while (0)

    STAGE2(0); STAGE2(1); STAGE2(2);

    float qE[4][4], qO[4][4];
    #pragma unroll
    for (int nb = 0; nb < 4; ++nb)
        #pragma unroll
        for (int rr = 0; rr < 4; ++rr) { qE[nb][rr] = 0.f; qO[nb][rr] = 0.f; }

    const int xo = (l15 & 7) << 4;       // read-side swizzle term

    #pragma unroll
    for (int p = 0; p < 32; ++p) {
        // counted wait: my outstanding = 2 insts per in-flight chunk
        if (p <= 29)      asm volatile("s_waitcnt vmcnt(4)" ::: "memory");
        else if (p == 30) asm volatile("s_waitcnt vmcnt(2)" ::: "memory");
        else              asm volatile("s_waitcnt vmcnt(0)" ::: "memory");
        __builtin_amdgcn_s_barrier();
        asm volatile("" ::: "memory");
        __builtin_amdgcn_sched_barrier(0);
        if (p + 3 < 32) STAGE2(p + 3);   // slot (p+3)&3 == (p-1)&3: freed by barrier

        const char* sb = (const char*)&vs[p & 3][0];
        #pragma unroll
        for (int nb = 0; nb < 4; ++nb) {
            int rowb = (l15 + nb * 16) * 128;
            v8bf b0 = ld_bf8((const unsigned short*)(sb + rowb + ((lh * 16) ^ xo)));
            v8bf b1 = ld_bf8((const unsigned short*)(sb + rowb + ((64 + lh * 16) ^ xo)));
            v4f z = (v4f){0.f, 0.f, 0.f, 0.f};
            v4f r = MFMA16(a0, b0, z);
            r     = MFMA16(a1, b1, r);
            if (p & 1) {
                #pragma unroll
                for (int rr = 0; rr < 4; ++rr) qO[nb][rr] += r[rr] * r[rr];
            } else {
                #pragma unroll
                for (int rr = 0; rr < 4; ++rr) qE[nb][rr] += r[rr] * r[rr];
            }
        }
    }

    // ---- 7-bit WHT per token row (r4-verified epilogue) ----
    #pragma unroll
    for (int rr = 0; rr < 4; ++rr) {
        float w8[8];
        #pragma unroll
        for (int nb = 0; nb < 4; ++nb) { w8[nb] = qE[nb][rr]; w8[4 + nb] = qO[nb][rr]; }

        #pragma unroll
        for (int i = 0; i < 4; ++i) {                 // bit6 (chunk parity)
            float u = w8[i], v = w8[i + 4];
            w8[i] = u + v; w8[i + 4] = u - v;
        }
        #pragma unroll
        for (int g = 0; g < 8; g += 4)                // bit5 (nb bit1)
            #pragma unroll
            for (int i = 0; i < 2; ++i) {
                float u = w8[g + i], v = w8[g + i + 2];
                w8[g + i] = u + v; w8[g + i + 2] = u - v;
            }
        #pragma unroll
        for (int g = 0; g < 8; g += 2) {              // bit4 (nb bit0)
            float u = w8[g], v = w8[g + 1];
            w8[g] = u + v; w8[g + 1] = u - v;
        }
        #pragma unroll
        for (int st = 1; st <= 8; st <<= 1) {         // bits 3..0 (l15) cross-lane
            #pragma unroll
            for (int k = 0; k < 8; ++k) {
                float o = __shfl_xor(w8[k], st);
                w8[k] = (l15 & st) ? (o - w8[k]) : (w8[k] + o);
            }
        }
        float* orow = out + (size_t)(tb + lh * 4 + rr) * 64;
        #pragma unroll
        for (int nb = 0; nb < 4; ++nb)
            if (nb != 0 || l15 != 0) orow[nb * 16 + l15 - 1] = w8[nb];  // m -> h=m-1
        if (l15 == 0) orow[63] = w8[4];                                  // m=64 -> h=63
    }
#undef STAGE2
}

extern "C" void kernel_launch(void* const* d_in, const int* in_sizes, int n_in,
                              void* d_out, int out_size, void* d_ws, size_t ws_size,
                              hipStream_t stream) {
    const float* x   = (const float*)d_in[0];
    const float* rx0 = (const float*)d_in[1];
    const float* ry0 = (const float*)d_in[2];
    const float* ry1 = (const float*)d_in[3];
    float* out = (float*)d_out;

    unsigned short* Vre = (unsigned short*)d_ws;   // 1024x64 bf16
    unsigned short* Vim = Vre + 1024 * 64;         // 1024x64 bf16 (contiguous -> stacked VS)

    const int M = in_sizes[0] / 64;                // tokens (B*T)

    build_V<<<4, 1024, 0, stream>>>(rx0, ry0, ry1, Vre, Vim);
    qsa_fused<<<M / 64, 256, 0, stream>>>(x, Vre, out);
}

// Round 8
// 88.601 us; speedup vs baseline: 2.6818x; 2.6818x over previous
//
#include <hip/hip_runtime.h>

typedef __bf16 v8bf __attribute__((ext_vector_type(8)));
typedef float v4f __attribute__((ext_vector_type(4)));
typedef unsigned short u16x8 __attribute__((ext_vector_type(8)));

__device__ __forceinline__ unsigned short f2bf(float f) {
    unsigned int u = __float_as_uint(f);
    u += 0x7FFFu + ((u >> 16) & 1u);   // round-to-nearest-even
    return (unsigned short)(u >> 16);
}

__device__ __forceinline__ v8bf ld_bf8(const unsigned short* p) {
    u16x8 r = *(const u16x8*)p;
    return __builtin_bit_cast(v8bf, r);
}

// HW trig: v_cos/v_sin take revolutions (x*2pi). cos(h) -> r = h/(2pi).
// Args here are h in [0, pi] -> r in [0, 0.5]: no reduction needed.
// Accuracy ~2^-20 abs — far below bf16 quantization of V.
__device__ __forceinline__ float hw_cos(float h) {
    float r = h * 0.15915494309189535f, o;
    asm("v_cos_f32 %0, %1" : "=v"(o) : "v"(r));
    return o;
}
__device__ __forceinline__ float hw_sin(float h) {
    float r = h * 0.15915494309189535f, o;
    asm("v_sin_f32 %0, %1" : "=v"(o) : "v"(r));
    return o;
}

// ---------------- Kernel A: build V = U[:, :64], one WAVE per column ----------------
// r5-verified math (product-state + CNOT-ring permutation + RY1 butterflies).
// ONLY change vs r5: libm cosf/sinf -> raw v_cos/v_sin inline asm (the ~68 us
// invariant across r2/r5/r6 scaled with per-column trig count; libm-call theory).
__global__ __launch_bounds__(64, 2) void build_V(
        const float* __restrict__ rx0, const float* __restrict__ ry0,
        const float* __restrict__ ry1,
        unsigned short* __restrict__ Vre, unsigned short* __restrict__ Vim)
{
    const int c = blockIdx.x;          // column 0..63
    const int lane = threadIdx.x;      // 0..63

    float c1[10], s1[10];
    #pragma unroll
    for (int j = 0; j < 10; ++j) {
        float h = 0.5f * ry1[j];
        c1[j] = hw_cos(h); s1[j] = hw_sin(h);
    }

    // k[q] = Pinv(m), m = lane + 64*q (CNOT ring inverse: bit-XOR network)
    int kk[16];
    #pragma unroll
    for (int q = 0; q < 16; ++q) {
        int k = lane + (q << 6);
        #pragma unroll
        for (int jj = 9; jj >= 0; --jj) {
            int cb = 9 - jj, tb = 9 - ((jj + 1) % 10);
            k ^= ((k >> cb) & 1) << tb;
        }
        kk[q] = k;
    }

    float ar[16], ai[16];
    #pragma unroll
    for (int q = 0; q < 16; ++q) { ar[q] = 1.f; ai[q] = 0.f; }

    #pragma unroll
    for (int j = 0; j < 10; ++j) {
        float hx = 0.5f * rx0[j], hy = 0.5f * ry0[j];
        float cx = hw_cos(hx), sx = hw_sin(hx), cy = hw_cos(hy), sy = hw_sin(hy);
        int cb = (c >> (9 - j)) & 1;
        float g0r = cb ? (-sy * cx) : (cy * cx);
        float g0i = cb ? (-cy * sx) : (sy * sx);
        float g1r = cb ? (cy * cx)  : (sy * cx);
        float g1i = cb ? (-sy * sx) : (-cy * sx);
        int p = 9 - j;
        #pragma unroll
        for (int q = 0; q < 16; ++q) {
            int kb = (kk[q] >> p) & 1;
            float fr = kb ? g1r : g0r;
            float fi = kb ? g1i : g0i;
            float nr = ar[q] * fr - ai[q] * fi;
            float ni = ar[q] * fi + ai[q] * fr;
            ar[q] = nr; ai[q] = ni;
        }
    }

    // RY1 on m bits 6..9 (q bits, qubit j = 3-b)
    #pragma unroll
    for (int b = 0; b < 4; ++b) {
        float cy = c1[3 - b], sy = s1[3 - b];
        #pragma unroll
        for (int q = 0; q < 16; ++q) {
            if (q & (1 << b)) continue;
            int q2 = q | (1 << b);
            float A_r = ar[q], A_i = ai[q], B_r = ar[q2], B_i = ai[q2];
            ar[q]  = cy * A_r - sy * B_r;  ai[q]  = cy * A_i - sy * B_i;
            ar[q2] = sy * A_r + cy * B_r;  ai[q2] = sy * A_i + cy * B_i;
        }
    }
    // RY1 on m bits 0..5 (lane bits, qubit j = 9-p) via shfl_xor
    #pragma unroll
    for (int p = 5; p >= 0; --p) {
        float cy = c1[9 - p], sy = s1[9 - p];
        int hi = (lane >> p) & 1;
        #pragma unroll
        for (int q = 0; q < 16; ++q) {
            float orr = __shfl_xor(ar[q], 1 << p);
            float oii = __shfl_xor(ai[q], 1 << p);
            ar[q] = hi ? (sy * orr + cy * ar[q]) : (cy * ar[q] - sy * orr);
            ai[q] = hi ? (sy * oii + cy * ai[q]) : (cy * ai[q] - sy * oii);
        }
    }

    #pragma unroll
    for (int q = 0; q < 16; ++q) {
        int i = lane + (q << 6);
        Vre[i * 64 + c] = f2bf(ar[q]);
        Vim[i * 64 + c] = f2bf(ai[q]);
    }
}

// ---------------- Kernel B: out = WHT_7( fold_128( |xn @ VS^T|^2 ) ) ----------------
// r2-PROVEN staging structure (plain u16x8 loads -> padded LDS, dbuf, one
// barrier per chunk; FETCH stayed 3.1 MB in r2) + r4-verified WHT epilogue
// (removes matmul2 / sign-gen / probs LDS roundtrip entirely).
// VS = [Vre; Vim] stacked 2048x64 = 32 chunks of 64x64. Block = 4 waves,
// 64 tokens (wave w owns tokens 16w..16w+15), all waves share staged V.
#define MFMA16(a, b, c) __builtin_amdgcn_mfma_f32_16x16x32_bf16(a, b, c, 0, 0, 0)

__global__ __launch_bounds__(256, 4) void qsa_fused(
        const float* __restrict__ x,
        const unsigned short* __restrict__ VS,
        float* __restrict__ out)
{
    __shared__ unsigned short vs[2][64][72];   // 18.4 KB, padded rows (144 B)

    const int tid = threadIdx.x;
    const int w = tid >> 6, l = tid & 63;
    const int l15 = l & 15, lh = l >> 4;
    const int tb = blockIdx.x * 64 + w * 16;   // this wave's 16 token rows

    // staging coords: thread -> (row tid>>2, 32 B segment (tid&3)*16 elems)
    const int srow = tid >> 2;
    const int scol = (tid & 3) * 16;
    const unsigned short* sg = VS + srow * 64 + scol;

    // ---- load + normalize 16 tokens into A-fragments (r2-proven) ----
    const float* xrow = x + (size_t)(tb + l15) * 64;
    float4 v0 = *(const float4*)(xrow + lh * 8);
    float4 v1 = *(const float4*)(xrow + lh * 8 + 4);
    float4 v2 = *(const float4*)(xrow + 32 + lh * 8);
    float4 v3 = *(const float4*)(xrow + 32 + lh * 8 + 4);
    float ss = v0.x*v0.x + v0.y*v0.y + v0.z*v0.z + v0.w*v0.w
             + v1.x*v1.x + v1.y*v1.y + v1.z*v1.z + v1.w*v1.w
             + v2.x*v2.x + v2.y*v2.y + v2.z*v2.z + v2.w*v2.w
             + v3.x*v3.x + v3.y*v3.y + v3.z*v3.z + v3.w*v3.w;
    ss += __shfl_xor(ss, 16);
    ss += __shfl_xor(ss, 32);
    float rn = rsqrtf(ss);
    u16x8 ua0, ua1;
    ua0[0]=f2bf(v0.x*rn); ua0[1]=f2bf(v0.y*rn); ua0[2]=f2bf(v0.z*rn); ua0[3]=f2bf(v0.w*rn);
    ua0[4]=f2bf(v1.x*rn); ua0[5]=f2bf(v1.y*rn); ua0[6]=f2bf(v1.z*rn); ua0[7]=f2bf(v1.w*rn);
    ua1[0]=f2bf(v2.x*rn); ua1[1]=f2bf(v2.y*rn); ua1[2]=f2bf(v2.z*rn); ua1[3]=f2bf(v2.w*rn);
    ua1[4]=f2bf(v3.x*rn); ua1[5]=f2bf(v3.y*rn); ua1[6]=f2bf(v3.z*rn); ua1[7]=f2bf(v3.w*rn);
    const v8bf a0 = __builtin_bit_cast(v8bf, ua0);
    const v8bf a1 = __builtin_bit_cast(v8bf, ua1);

    float qE[4][4], qO[4][4];
    #pragma unroll
    for (int nb = 0; nb < 4; ++nb)
        #pragma unroll
        for (int rr = 0; rr < 4; ++rr) { qE[nb][rr] = 0.f; qO[nb][rr] = 0.f; }

    // prologue: stage chunk 0
    {
        u16x8 d0 = *(const u16x8*)(sg);
        u16x8 d1 = *(const u16x8*)(sg + 8);
        *(u16x8*)&vs[0][srow][scol] = d0;
        *(u16x8*)&vs[0][srow][scol + 8] = d1;
    }
    __syncthreads();

    #pragma unroll 2
    for (int p = 0; p < 32; ++p) {
        // stage next chunk into the other slot (no hazard: different slot)
        if (p + 1 < 32) {
            const unsigned short* gp = sg + (size_t)(p + 1) * 4096;
            u16x8 d0 = *(const u16x8*)(gp);
            u16x8 d1 = *(const u16x8*)(gp + 8);
            *(u16x8*)&vs[(p + 1) & 1][srow][scol] = d0;
            *(u16x8*)&vs[(p + 1) & 1][srow][scol + 8] = d1;
        }
        // compute chunk p: 8 MFMA, fold |psi|^2 into 128 bins (parity = p&1)
        const unsigned short (*vb)[72] = vs[p & 1];
        #pragma unroll
        for (int nb = 0; nb < 4; ++nb) {
            v8bf b0 = ld_bf8(&vb[nb * 16 + l15][lh * 8]);
            v8bf b1 = ld_bf8(&vb[nb * 16 + l15][32 + lh * 8]);
            v4f z = (v4f){0.f, 0.f, 0.f, 0.f};
            v4f r = MFMA16(a0, b0, z);
            r     = MFMA16(a1, b1, r);
            if (p & 1) {
                #pragma unroll
                for (int rr = 0; rr < 4; ++rr) qO[nb][rr] += r[rr] * r[rr];
            } else {
                #pragma unroll
                for (int rr = 0; rr < 4; ++rr) qE[nb][rr] += r[rr] * r[rr];
            }
        }
        __syncthreads();   // stage(p+1) visible; reads of slot p done before p+2 overwrite
    }

    // ---- 7-bit WHT per token row (r4-verified epilogue) ----
    #pragma unroll
    for (int rr = 0; rr < 4; ++rr) {
        float w8[8];
        #pragma unroll
        for (int nb = 0; nb < 4; ++nb) { w8[nb] = qE[nb][rr]; w8[4 + nb] = qO[nb][rr]; }

        #pragma unroll
        for (int i = 0; i < 4; ++i) {                 // bit6 (chunk parity)
            float u = w8[i], v = w8[i + 4];
            w8[i] = u + v; w8[i + 4] = u - v;
        }
        #pragma unroll
        for (int g = 0; g < 8; g += 4)                // bit5 (nb bit1)
            #pragma unroll
            for (int i = 0; i < 2; ++i) {
                float u = w8[g + i], v = w8[g + i + 2];
                w8[g + i] = u + v; w8[g + i + 2] = u - v;
            }
        #pragma unroll
        for (int g = 0; g < 8; g += 2) {              // bit4 (nb bit0)
            float u = w8[g], v = w8[g + 1];
            w8[g] = u + v; w8[g + 1] = u - v;
        }
        #pragma unroll
        for (int st = 1; st <= 8; st <<= 1) {         // bits 3..0 (l15) cross-lane
            #pragma unroll
            for (int k = 0; k < 8; ++k) {
                float o = __shfl_xor(w8[k], st);
                w8[k] = (l15 & st) ? (o - w8[k]) : (w8[k] + o);
            }
        }
        float* orow = out + (size_t)(tb + lh * 4 + rr) * 64;
        #pragma unroll
        for (int nb = 0; nb < 4; ++nb)
            if (nb != 0 || l15 != 0) orow[nb * 16 + l15 - 1] = w8[nb];  // m -> h=m-1
        if (l15 == 0) orow[63] = w8[4];                                  // m=64 -> h=63
    }
}

extern "C" void kernel_launch(void* const* d_in, const int* in_sizes, int n_in,
                              void* d_out, int out_size, void* d_ws, size_t ws_size,
                              hipStream_t stream) {
    const float* x   = (const float*)d_in[0];
    const float* rx0 = (const float*)d_in[1];
    const float* ry0 = (const float*)d_in[2];
    const float* ry1 = (const float*)d_in[3];
    float* out = (float*)d_out;

    unsigned short* Vre = (unsigned short*)d_ws;   // 1024x64 bf16
    unsigned short* Vim = Vre + 1024 * 64;         // 1024x64 bf16 (contiguous -> stacked VS)

    const int M = in_sizes[0] / 64;                // tokens (B*T)

    build_V<<<64, 64, 0, stream>>>(rx0, ry0, ry1, Vre, Vim);
    qsa_fused<<<M / 64, 256, 0, stream>>>(x, Vre, out);
}